// Round 10
// baseline (19.069 us; speedup 1.0000x reference)
//
#include <hip/hip_runtime.h>

// x [B=8, C=8, H=256, W=256] f32, theta [O=8, 2, 3] f32 -> out [B=8, O=8, H=256, W=256] f32.
#define BDIM 8
#define CDIM 8
#define ODIM 8
#define HDIM 256
#define WDIM 256
#define HW   (HDIM * WDIM)      // 65536

typedef unsigned int u32;

__device__ __forceinline__ u32 bf16r(float f) {          // f32 -> bf16 bits, RNE
    u32 u = __float_as_uint(f);
    return (u + 0x7FFFu + ((u >> 16) & 1u)) >> 16;
}
__device__ __forceinline__ u32 pack2(float a, float b) { // b in hi16
    return bf16r(a) | (bf16r(b) << 16);
}
__device__ __forceinline__ float lo16(u32 u) { return __uint_as_float(u << 16); }
__device__ __forceinline__ float hi16(u32 u) { return __uint_as_float(u & 0xFFFF0000u); }

// Kernel 1: tex[y][x] = {bf16(mean_c x[b,c,y,x]) for b=0..7} (16B per position).
// Mean-over-c commutes with the (linear, c-independent) bilinear sampler;
// SoA-in-b lets one dwordx4 gather serve all 8 batches (R9: 23->16.8us).
__global__ __launch_bounds__(256) void meanpack_kernel(const float* __restrict__ x,
                                                       uint4* __restrict__ tex) {
    int t = blockIdx.x * 256 + threadIdx.x;   // position (y<<8)+x ; lanes = consecutive x
    float s[BDIM];
#pragma unroll
    for (int b = 0; b < BDIM; ++b) {
        float acc = 0.f;
#pragma unroll
        for (int c = 0; c < CDIM; ++c)
            acc += x[(((size_t)(b * CDIM + c)) << 16) + t];   // coalesced per (b,c)
        s[b] = acc * (1.0f / CDIM);
    }
    uint4 q;
    q.x = pack2(s[0], s[1]);
    q.y = pack2(s[2], s[3]);
    q.z = pack2(s[4], s[5]);
    q.w = pack2(s[6], s[7]);
    tex[t] = q;                               // coalesced 16B store
}

// Kernel 2: one thread per (o,h,w) in 8x8-per-wave 2D tiles; grid math once,
// 4 dwordx4 tap gathers, 8 outputs (all b) via nontemporal stores.
// 2D wave tiling shrinks the per-wave gather line footprint ~2.5x vs a row
// strip (test of the L1<->L2 line-traffic model). Shifted-weight validity
// (validated R7-R9): invalid taps get weight 0, clamped addrs never contribute.
__global__ __launch_bounds__(256) void sample_kernel(const uint4* __restrict__ tex,
                                                     const float* __restrict__ theta,
                                                     float* __restrict__ out) {
    int o  = blockIdx.y;
    int tx = blockIdx.x & 15;        // 16 tiles of 16 px across W
    int ty = blockIdx.x >> 4;        // 16 tiles of 16 px across H
    int wave = threadIdx.x >> 6;     // 2x2 waves in the block
    int lane = threadIdx.x & 63;
    int h = (ty << 4) + ((wave >> 1) << 3) + (lane >> 3);
    int w = (tx << 4) + ((wave & 1) << 3) + (lane & 7);
    int hw = (h << 8) + w;

    float t00 = theta[o * 6 + 0], t01 = theta[o * 6 + 1], t02 = theta[o * 6 + 2];
    float t10 = theta[o * 6 + 3], t11 = theta[o * 6 + 4], t12 = theta[o * 6 + 5];

    // linspace(-1,1,256): step 2/255 (matches reference numerics)
    float xs = -1.0f + (float)w * (2.0f / 255.0f);
    float ys = -1.0f + (float)h * (2.0f / 255.0f);
    float gx = t00 * xs + t01 * ys + t02;
    float gy = t10 * xs + t11 * ys + t12;
    float ix = (gx + 1.0f) * 0.5f * (WDIM - 1);
    float iy = (gy + 1.0f) * 0.5f * (HDIM - 1);

    float fx = floorf(ix), fy = floorf(iy);
    float wx1 = ix - fx, wx0 = 1.0f - wx1;
    float wy1 = iy - fy, wy0 = 1.0f - wy1;

    bool vx0 = (fx >= 0.0f)  && (fx <= 255.0f);
    bool vx1 = (fx >= -1.0f) && (fx <= 254.0f);
    bool vy0 = (fy >= 0.0f)  && (fy <= 255.0f);
    bool vy1 = (fy >= -1.0f) && (fy <= 254.0f);

    float wxA = vx0 ? wx0 : ((fx == -1.0f) ? wx1 : 0.0f);
    float wxB = (vx0 && vx1) ? wx1 : 0.0f;
    float wyA = vy0 ? wy0 : ((fy == -1.0f) ? wy1 : 0.0f);
    float wyB = (vy0 && vy1) ? wy1 : 0.0f;

    int bxA = min(max((int)fx, 0), WDIM - 1);
    int bxB = min(bxA + 1, WDIM - 1);
    int byA = min(max((int)fy, 0), HDIM - 1);
    int byB = min(byA + 1, HDIM - 1);

    uint4 q00 = tex[(byA << 8) + bxA];
    uint4 q01 = tex[(byA << 8) + bxB];
    uint4 q10 = tex[(byB << 8) + bxA];
    uint4 q11 = tex[(byB << 8) + bxB];

    float wAA = wyA * wxA, wAB = wyA * wxB;
    float wBA = wyB * wxA, wBB = wyB * wxB;

    size_t obase = (((size_t)o) << 16) + hw;   // out idx = ((b*ODIM+o)<<16)+hw

#define EMIT(K, COMP)                                                              \
    {                                                                              \
        float vl = wAA * lo16(q00.COMP) + wAB * lo16(q01.COMP)                     \
                 + wBA * lo16(q10.COMP) + wBB * lo16(q11.COMP);                    \
        float vh = wAA * hi16(q00.COMP) + wAB * hi16(q01.COMP)                     \
                 + wBA * hi16(q10.COMP) + wBB * hi16(q11.COMP);                    \
        __builtin_nontemporal_store(vl, &out[(((size_t)(2 * K) * ODIM) << 16) + obase]);      \
        __builtin_nontemporal_store(vh, &out[(((size_t)(2 * K + 1) * ODIM) << 16) + obase]);  \
    }
    EMIT(0, x) EMIT(1, y) EMIT(2, z) EMIT(3, w)
#undef EMIT
}

extern "C" void kernel_launch(void* const* d_in, const int* in_sizes, int n_in,
                              void* d_out, int out_size, void* d_ws, size_t ws_size,
                              hipStream_t stream) {
    const float* x     = (const float*)d_in[0];
    const float* theta = (const float*)d_in[1];
    float* out = (float*)d_out;
    uint4* tex = (uint4*)d_ws;    // HW * 16B = 1 MiB scratch (L2-resident)

    meanpack_kernel<<<dim3(HW / 256), dim3(256), 0, stream>>>(x, tex);

    dim3 grid(HW / 256, ODIM);    // 256 16x16 tiles per plane, one o per blockIdx.y
    sample_kernel<<<grid, dim3(256), 0, stream>>>(tex, theta, out);
}

// Round 12
// 16.343 us; speedup vs baseline: 1.1668x; 1.1668x over previous
//
#include <hip/hip_runtime.h>

// x [B=8, C=8, H=256, W=256] f32, theta [O=8, 2, 3] f32 -> out [B=8, O=8, H=256, W=256] f32.
#define BDIM 8
#define CDIM 8
#define ODIM 8
#define HDIM 256
#define WDIM 256
#define HW   (HDIM * WDIM)      // 65536

typedef unsigned int u32;

__device__ __forceinline__ u32 bf16r(float f) {          // f32 -> bf16 bits, RNE
    u32 u = __float_as_uint(f);
    return (u + 0x7FFFu + ((u >> 16) & 1u)) >> 16;
}
__device__ __forceinline__ u32 pack2(float a, float b) { // b in hi16
    return bf16r(a) | (bf16r(b) << 16);
}
__device__ __forceinline__ float lo16(u32 u) { return __uint_as_float(u << 16); }
__device__ __forceinline__ float hi16(u32 u) { return __uint_as_float(u & 0xFFFF0000u); }

// Kernel 1: tex[y][x] = {bf16(mean_c x[b,c,y,x]) for b=0..7} (16B per position).
// Mean-over-c commutes with the (linear, c-independent) bilinear sampler;
// SoA-in-b lets one dwordx4 gather serve all 8 batches (R9: 23->16.8us).
__global__ __launch_bounds__(256) void meanpack_kernel(const float* __restrict__ x,
                                                       uint4* __restrict__ tex) {
    int t = blockIdx.x * 256 + threadIdx.x;   // position (y<<8)+x ; lanes = consecutive x
    float s[BDIM];
#pragma unroll
    for (int b = 0; b < BDIM; ++b) {
        float acc = 0.f;
#pragma unroll
        for (int c = 0; c < CDIM; ++c)
            acc += x[(((size_t)(b * CDIM + c)) << 16) + t];   // coalesced per (b,c)
        s[b] = acc * (1.0f / CDIM);
    }
    uint4 q;
    q.x = pack2(s[0], s[1]);
    q.y = pack2(s[2], s[3]);
    q.z = pack2(s[4], s[5]);
    q.w = pack2(s[6], s[7]);
    tex[t] = q;                               // coalesced 16B store
}

// Per-position sampling state: shifted-weight validity scheme (validated
// R7-R9) -- wxA applies to column bxA=clamp(floor(ix)), wxB to bxA+1;
// invalid taps get weight 0 so clamped addresses never contribute.
struct Samp {
    float wxA, wxB, wyA, wyB;
    int a00, a01, a10, a11;     // tex indices of the 4 taps
};

__device__ __forceinline__ Samp make_samp(int hw, float t00, float t01, float t02,
                                          float t10, float t11, float t12) {
    int h = hw >> 8, w = hw & 255;
    float xs = -1.0f + (float)w * (2.0f / 255.0f);   // linspace(-1,1,256)
    float ys = -1.0f + (float)h * (2.0f / 255.0f);
    float ix = ((t00 * xs + t01 * ys + t02) + 1.0f) * 127.5f;
    float iy = ((t10 * xs + t11 * ys + t12) + 1.0f) * 127.5f;
    float fx = floorf(ix), fy = floorf(iy);
    float wx1 = ix - fx, wx0 = 1.0f - wx1;
    float wy1 = iy - fy, wy0 = 1.0f - wy1;
    bool vx0 = (fx >= 0.0f)  && (fx <= 255.0f);
    bool vx1 = (fx >= -1.0f) && (fx <= 254.0f);
    bool vy0 = (fy >= 0.0f)  && (fy <= 255.0f);
    bool vy1 = (fy >= -1.0f) && (fy <= 254.0f);
    Samp s;
    s.wxA = vx0 ? wx0 : ((fx == -1.0f) ? wx1 : 0.0f);
    s.wxB = (vx0 && vx1) ? wx1 : 0.0f;
    s.wyA = vy0 ? wy0 : ((fy == -1.0f) ? wy1 : 0.0f);
    s.wyB = (vy0 && vy1) ? wy1 : 0.0f;
    int bxA = min(max((int)fx, 0), WDIM - 1);
    int bxB = min(bxA + 1, WDIM - 1);
    int byA = min(max((int)fy, 0), HDIM - 1);
    int byB = min(byA + 1, HDIM - 1);
    s.a00 = (byA << 8) + bxA;
    s.a01 = (byA << 8) + bxB;
    s.a10 = (byB << 8) + bxA;
    s.a11 = (byB << 8) + bxB;
    return s;
}

// Kernel 2: TWO output positions per thread (hw and hw+256) -> 8 independent
// dwordx4 gathers in flight (MLP test: is the gather phase latency-bound?).
// 16 outputs/thread. Flat mapping (R9): lanes = consecutive w -> each
// wave-store is one 256B span; nontemporal full-line stores skip L2
// write-allocate, keeping L2 for tex.
__global__ __launch_bounds__(256) void sample_kernel(const uint4* __restrict__ tex,
                                                     const float* __restrict__ theta,
                                                     float* __restrict__ out) {
    int tid = threadIdx.x;
    int o   = blockIdx.y;
    int hwA = blockIdx.x * 512 + tid;
    int hwB = hwA + 256;

    float t00 = theta[o * 6 + 0], t01 = theta[o * 6 + 1], t02 = theta[o * 6 + 2];
    float t10 = theta[o * 6 + 3], t11 = theta[o * 6 + 4], t12 = theta[o * 6 + 5];

    Samp sA = make_samp(hwA, t00, t01, t02, t10, t11, t12);
    Samp sB = make_samp(hwB, t00, t01, t02, t10, t11, t12);

    // all 8 independent gathers issued before any use
    uint4 qA00 = tex[sA.a00];
    uint4 qA01 = tex[sA.a01];
    uint4 qA10 = tex[sA.a10];
    uint4 qA11 = tex[sA.a11];
    uint4 qB00 = tex[sB.a00];
    uint4 qB01 = tex[sB.a01];
    uint4 qB10 = tex[sB.a10];
    uint4 qB11 = tex[sB.a11];

    {
        float wAA = sA.wyA * sA.wxA, wAB = sA.wyA * sA.wxB;
        float wBA = sA.wyB * sA.wxA, wBB = sA.wyB * sA.wxB;
        size_t obase = (((size_t)o) << 16) + hwA;
#pragma unroll
        for (int k = 0; k < 4; ++k) {
            u32 c00 = (&qA00.x)[k], c01 = (&qA01.x)[k];
            u32 c10 = (&qA10.x)[k], c11 = (&qA11.x)[k];
            float vl = wAA * lo16(c00) + wAB * lo16(c01)
                     + wBA * lo16(c10) + wBB * lo16(c11);
            float vh = wAA * hi16(c00) + wAB * hi16(c01)
                     + wBA * hi16(c10) + wBB * hi16(c11);
            __builtin_nontemporal_store(vl, &out[(((size_t)(2 * k) * ODIM) << 16) + obase]);
            __builtin_nontemporal_store(vh, &out[(((size_t)(2 * k + 1) * ODIM) << 16) + obase]);
        }
    }
    {
        float wAA = sB.wyA * sB.wxA, wAB = sB.wyA * sB.wxB;
        float wBA = sB.wyB * sB.wxA, wBB = sB.wyB * sB.wxB;
        size_t obase = (((size_t)o) << 16) + hwB;
#pragma unroll
        for (int k = 0; k < 4; ++k) {
            u32 c00 = (&qB00.x)[k], c01 = (&qB01.x)[k];
            u32 c10 = (&qB10.x)[k], c11 = (&qB11.x)[k];
            float vl = wAA * lo16(c00) + wAB * lo16(c01)
                     + wBA * lo16(c10) + wBB * lo16(c11);
            float vh = wAA * hi16(c00) + wAB * hi16(c01)
                     + wBA * hi16(c10) + wBB * hi16(c11);
            __builtin_nontemporal_store(vl, &out[(((size_t)(2 * k) * ODIM) << 16) + obase]);
            __builtin_nontemporal_store(vh, &out[(((size_t)(2 * k + 1) * ODIM) << 16) + obase]);
        }
    }
}

extern "C" void kernel_launch(void* const* d_in, const int* in_sizes, int n_in,
                              void* d_out, int out_size, void* d_ws, size_t ws_size,
                              hipStream_t stream) {
    const float* x     = (const float*)d_in[0];
    const float* theta = (const float*)d_in[1];
    float* out = (float*)d_out;
    uint4* tex = (uint4*)d_ws;    // HW * 16B = 1 MiB scratch (L2-resident)

    meanpack_kernel<<<dim3(HW / 256), dim3(256), 0, stream>>>(x, tex);

    dim3 grid(HW / 512, ODIM);    // 128 x 8 blocks; 2 positions per thread
    sample_kernel<<<grid, dim3(256), 0, stream>>>(tex, theta, out);
}

// Round 13
// 16.341 us; speedup vs baseline: 1.1669x; 1.0001x over previous
//
#include <hip/hip_runtime.h>

// x [B=8, C=8, H=256, W=256] f32, theta [O=8, 2, 3] f32 -> out [B=8, O=8, H=256, W=256] f32.
#define BDIM 8
#define CDIM 8
#define ODIM 8
#define HDIM 256
#define WDIM 256
#define HW   (HDIM * WDIM)      // 65536

typedef unsigned int u32;

__device__ __forceinline__ u32 bf16r(float f) {          // f32 -> bf16 bits, RNE
    u32 u = __float_as_uint(f);
    return (u + 0x7FFFu + ((u >> 16) & 1u)) >> 16;
}
__device__ __forceinline__ u32 pack2(float a, float b) { // b in hi16
    return bf16r(a) | (bf16r(b) << 16);
}
__device__ __forceinline__ float lo16(u32 u) { return __uint_as_float(u << 16); }
__device__ __forceinline__ float hi16(u32 u) { return __uint_as_float(u & 0xFFFF0000u); }

// Kernel 1: tex[y][x] = {bf16(mean_c x[b,c,y,x]) for b=0..7} (16B per position).
// Mean-over-c commutes with the (linear, c-independent) bilinear sampler;
// SoA-in-b lets one dwordx4 gather serve all 8 batches (R9: 23->16.8us).
__global__ __launch_bounds__(256) void meanpack_kernel(const float* __restrict__ x,
                                                       uint4* __restrict__ tex) {
    int t = blockIdx.x * 256 + threadIdx.x;   // position (y<<8)+x ; lanes = consecutive x
    float s[BDIM];
#pragma unroll
    for (int b = 0; b < BDIM; ++b) {
        float acc = 0.f;
#pragma unroll
        for (int c = 0; c < CDIM; ++c)
            acc += x[(((size_t)(b * CDIM + c)) << 16) + t];   // coalesced per (b,c)
        s[b] = acc * (1.0f / CDIM);
    }
    uint4 q;
    q.x = pack2(s[0], s[1]);
    q.y = pack2(s[2], s[3]);
    q.z = pack2(s[4], s[5]);
    q.w = pack2(s[6], s[7]);
    tex[t] = q;                               // coalesced 16B store
}

// Per-position sampling state: shifted-weight validity scheme (validated
// R7-R12) -- wxA applies to column bxA=clamp(floor(ix)), wxB to bxA+1;
// invalid taps get weight 0 so clamped addresses never contribute.
struct Samp {
    float wxA, wxB, wyA, wyB;
    int a00, a01, a10, a11;     // tex indices of the 4 taps
};

__device__ __forceinline__ Samp make_samp(int hw, float t00, float t01, float t02,
                                          float t10, float t11, float t12) {
    int h = hw >> 8, w = hw & 255;
    float xs = -1.0f + (float)w * (2.0f / 255.0f);   // linspace(-1,1,256)
    float ys = -1.0f + (float)h * (2.0f / 255.0f);
    float ix = ((t00 * xs + t01 * ys + t02) + 1.0f) * 127.5f;
    float iy = ((t10 * xs + t11 * ys + t12) + 1.0f) * 127.5f;
    float fx = floorf(ix), fy = floorf(iy);
    float wx1 = ix - fx, wx0 = 1.0f - wx1;
    float wy1 = iy - fy, wy0 = 1.0f - wy1;
    bool vx0 = (fx >= 0.0f)  && (fx <= 255.0f);
    bool vx1 = (fx >= -1.0f) && (fx <= 254.0f);
    bool vy0 = (fy >= 0.0f)  && (fy <= 255.0f);
    bool vy1 = (fy >= -1.0f) && (fy <= 254.0f);
    Samp s;
    s.wxA = vx0 ? wx0 : ((fx == -1.0f) ? wx1 : 0.0f);
    s.wxB = (vx0 && vx1) ? wx1 : 0.0f;
    s.wyA = vy0 ? wy0 : ((fy == -1.0f) ? wy1 : 0.0f);
    s.wyB = (vy0 && vy1) ? wy1 : 0.0f;
    int bxA = min(max((int)fx, 0), WDIM - 1);
    int bxB = min(bxA + 1, WDIM - 1);
    int byA = min(max((int)fy, 0), HDIM - 1);
    int byB = min(byA + 1, HDIM - 1);
    s.a00 = (byA << 8) + bxA;
    s.a01 = (byA << 8) + bxB;
    s.a10 = (byB << 8) + bxA;
    s.a11 = (byB << 8) + bxB;
    return s;
}

__device__ __forceinline__ void combine_store(const Samp& s, int hw, int o,
                                              uint4 q00, uint4 q01, uint4 q10, uint4 q11,
                                              float* __restrict__ out) {
    float wAA = s.wyA * s.wxA, wAB = s.wyA * s.wxB;
    float wBA = s.wyB * s.wxA, wBB = s.wyB * s.wxB;
    size_t obase = (((size_t)o) << 16) + hw;   // out idx = ((b*ODIM+o)<<16)+hw
#pragma unroll
    for (int k = 0; k < 4; ++k) {
        u32 c00 = (&q00.x)[k], c01 = (&q01.x)[k];
        u32 c10 = (&q10.x)[k], c11 = (&q11.x)[k];
        float vl = wAA * lo16(c00) + wAB * lo16(c01)
                 + wBA * lo16(c10) + wBB * lo16(c11);
        float vh = wAA * hi16(c00) + wAB * hi16(c01)
                 + wBA * hi16(c10) + wBB * hi16(c11);
        __builtin_nontemporal_store(vl, &out[(((size_t)(2 * k) * ODIM) << 16) + obase]);
        __builtin_nontemporal_store(vh, &out[(((size_t)(2 * k + 1) * ODIM) << 16) + obase]);
    }
}

// Kernel 2: FOUR output positions per thread -> 16 independent dwordx4
// gathers in flight before any combine (final MLP probe of the
// throughput-bound model). 32 outputs/thread. Flat mapping (R9): lanes =
// consecutive w -> each wave-store is one 256B span; nontemporal full-line
// stores skip L2 write-allocate, keeping L2 for tex.
__global__ __launch_bounds__(256) void sample_kernel(const uint4* __restrict__ tex,
                                                     const float* __restrict__ theta,
                                                     float* __restrict__ out) {
    int tid  = threadIdx.x;
    int o    = blockIdx.y;
    int base = blockIdx.x * 1024 + tid;

    float t00 = theta[o * 6 + 0], t01 = theta[o * 6 + 1], t02 = theta[o * 6 + 2];
    float t10 = theta[o * 6 + 3], t11 = theta[o * 6 + 4], t12 = theta[o * 6 + 5];

    Samp s0 = make_samp(base,       t00, t01, t02, t10, t11, t12);
    Samp s1 = make_samp(base + 256, t00, t01, t02, t10, t11, t12);
    Samp s2 = make_samp(base + 512, t00, t01, t02, t10, t11, t12);
    Samp s3 = make_samp(base + 768, t00, t01, t02, t10, t11, t12);

    // all 16 independent gathers issued before any use
    uint4 q000 = tex[s0.a00], q001 = tex[s0.a01], q010 = tex[s0.a10], q011 = tex[s0.a11];
    uint4 q100 = tex[s1.a00], q101 = tex[s1.a01], q110 = tex[s1.a10], q111 = tex[s1.a11];
    uint4 q200 = tex[s2.a00], q201 = tex[s2.a01], q210 = tex[s2.a10], q211 = tex[s2.a11];
    uint4 q300 = tex[s3.a00], q301 = tex[s3.a01], q310 = tex[s3.a10], q311 = tex[s3.a11];

    combine_store(s0, base,       o, q000, q001, q010, q011, out);
    combine_store(s1, base + 256, o, q100, q101, q110, q111, out);
    combine_store(s2, base + 512, o, q200, q201, q210, q211, out);
    combine_store(s3, base + 768, o, q300, q301, q310, q311, out);
}

extern "C" void kernel_launch(void* const* d_in, const int* in_sizes, int n_in,
                              void* d_out, int out_size, void* d_ws, size_t ws_size,
                              hipStream_t stream) {
    const float* x     = (const float*)d_in[0];
    const float* theta = (const float*)d_in[1];
    float* out = (float*)d_out;
    uint4* tex = (uint4*)d_ws;    // HW * 16B = 1 MiB scratch (L2-resident)

    meanpack_kernel<<<dim3(HW / 256), dim3(256), 0, stream>>>(x, tex);

    dim3 grid(HW / 1024, ODIM);   // 64 x 8 blocks; 4 positions per thread
    sample_kernel<<<grid, dim3(256), 0, stream>>>(tex, theta, out);
}